// Round 1
// baseline (574.703 us; speedup 1.0000x reference)
//
#include <hip/hip_runtime.h>

typedef __attribute__((ext_vector_type(4))) float f32x4;
typedef __attribute__((ext_vector_type(8))) short short8;
typedef __attribute__((ext_vector_type(4))) unsigned short ushort4v;

#define PMOD 113
#define NPAIR 12769      // 113*113
#define DM 1024
#define DMLP 4096
#define NBATCH 16384
#define TROWS 228        // 113 A-rows, 113 B-rows, row226=const, row227=b_out
#define SQRT3_2 0.86602540378443865f

__device__ __forceinline__ short f2bf(float x) {
    unsigned int u = __builtin_bit_cast(unsigned int, x);
    u += 0x7FFFu + ((u >> 16) & 1u);
    return (short)(u >> 16);
}

// ---------------------------------------------------------------------------
// Kernel A: build T[228][1024]:
//   t<113        : A_tab[t]  = Fc * E[t]
//   113<=t<226   : B_tab[t-113] = (-1/2 Fc + sqrt3/2 Fs) * E[t-113]
//   t==226       : const = e2 + Fc*(p0 - p1/2 - e2/2) + Fs*(sqrt3/2*(p1 - e2))
//   t==227       : copy of b_out (W_out_b)
// where e2 = E[113] + pos[2], Fc[f,d]=cos(2pi f d/1024), Fs[f,d]=sin(...)
// ---------------------------------------------------------------------------
__global__ __launch_bounds__(256) void k_tables(
    float* __restrict__ T, const float* __restrict__ E,
    const float* __restrict__ pos, const float* __restrict__ bout)
{
    const int t = blockIdx.x;
    const int tid = threadIdx.x;

    if (t == 227) {
        for (int f = tid; f < DM; f += 256) T[227 * DM + f] = bout[f];
        return;
    }

    __shared__ float ct[DM];
    __shared__ float vc[DM];
    __shared__ float vs[DM];

    for (int k = tid; k < DM; k += 256)
        ct[k] = cosf((float)k * 6.1359231515425649e-3f);  // 2*pi/1024

    bool has_sin;
    if (t < PMOD) {
        const float* e = E + t * DM;
        for (int d = tid; d < DM; d += 256) { vc[d] = e[d]; vs[d] = 0.f; }
        has_sin = false;
    } else if (t < 2 * PMOD) {
        const float* e = E + (t - PMOD) * DM;
        for (int d = tid; d < DM; d += 256) {
            float x = e[d];
            vc[d] = -0.5f * x;
            vs[d] = SQRT3_2 * x;
        }
        has_sin = true;
    } else {  // t == 226: const row
        const float* e2 = E + PMOD * DM;
        for (int d = tid; d < DM; d += 256) {
            float e2v = e2[d] + pos[2 * DM + d];
            vc[d] = pos[d] - 0.5f * pos[DM + d] - 0.5f * e2v;
            vs[d] = SQRT3_2 * (pos[DM + d] - e2v);
        }
        has_sin = true;
    }
    __syncthreads();

    const int f0 = tid, f1 = tid + 256, f2 = tid + 512, f3 = tid + 768;
    float a0 = 0.f, a1 = 0.f, a2 = 0.f, a3 = 0.f;
    int i0 = 0, i1 = 0, i2 = 0, i3 = 0;

    if (has_sin) {
        #pragma unroll 4
        for (int d = 0; d < DM; ++d) {
            float c = vc[d], s = vs[d];
            a0 += c * ct[i0] + s * ct[(i0 + 768) & 1023];
            a1 += c * ct[i1] + s * ct[(i1 + 768) & 1023];
            a2 += c * ct[i2] + s * ct[(i2 + 768) & 1023];
            a3 += c * ct[i3] + s * ct[(i3 + 768) & 1023];
            i0 = (i0 + f0) & 1023; i1 = (i1 + f1) & 1023;
            i2 = (i2 + f2) & 1023; i3 = (i3 + f3) & 1023;
        }
    } else {
        #pragma unroll 4
        for (int d = 0; d < DM; ++d) {
            float c = vc[d];
            a0 += c * ct[i0]; a1 += c * ct[i1];
            a2 += c * ct[i2]; a3 += c * ct[i3];
            i0 = (i0 + f0) & 1023; i1 = (i1 + f1) & 1023;
            i2 = (i2 + f2) & 1023; i3 = (i3 + f3) & 1023;
        }
    }

    if (t == 226) {
        const float* e2 = E + PMOD * DM;
        a0 += e2[f0] + pos[2 * DM + f0];
        a1 += e2[f1] + pos[2 * DM + f1];
        a2 += e2[f2] + pos[2 * DM + f2];
        a3 += e2[f3] + pos[2 * DM + f3];
    }
    T[t * DM + f0] = a0;
    T[t * DM + f1] = a1;
    T[t * DM + f2] = a2;
    T[t * DM + f3] = a3;
}

// ---------------------------------------------------------------------------
// NT GEMM: C[row, n] = sum_k A[row, k] * B[n, k],  A = T (228 x 1024, guarded)
// BM=64 (blockIdx.y), BN=128 (blockIdx.x), BK=32, K=1024. fp32.
// Used for: H[228][4096] = T * W_in^T (+bias on row 226)
//           L[228][128]  = T * U^T    (U zero-padded past 113 rows)
// ---------------------------------------------------------------------------
__global__ __launch_bounds__(256) void k_gemm_nt(
    float* __restrict__ C, int ldC,
    const float* __restrict__ A,
    const float* __restrict__ B, int Brows,
    const float* __restrict__ bias, int biasRow)
{
    __shared__ float Ta[32][68];    // [k][row]
    __shared__ float Wb[32][132];   // [k][n]

    const int tid = threadIdx.x;
    const int row0 = blockIdx.y * 64;
    const int n0 = blockIdx.x * 128;
    const int tr = tid >> 4, tm = tid & 15;

    const int sr = tid >> 2, sc = (tid & 3) * 8;      // A-stage: row sr, cols sc..sc+7
    const int wm = tid >> 1, wc0 = (tid & 1) * 16;    // B-stage: row wm, cols wc0..+15

    float acc[4][8];
    #pragma unroll
    for (int i = 0; i < 4; ++i)
        #pragma unroll
        for (int j = 0; j < 8; ++j) acc[i][j] = 0.f;

    for (int k0 = 0; k0 < DM; k0 += 32) {
        // stage A (transposed into [k][row])
        {
            float tmp[8];
            if (row0 + sr < TROWS) {
                const float* src = A + (row0 + sr) * DM + k0 + sc;
                f32x4 v0 = *(const f32x4*)(src);
                f32x4 v1 = *(const f32x4*)(src + 4);
                tmp[0]=v0[0]; tmp[1]=v0[1]; tmp[2]=v0[2]; tmp[3]=v0[3];
                tmp[4]=v1[0]; tmp[5]=v1[1]; tmp[6]=v1[2]; tmp[7]=v1[3];
            } else {
                #pragma unroll
                for (int c = 0; c < 8; ++c) tmp[c] = 0.f;
            }
            #pragma unroll
            for (int c = 0; c < 8; ++c) Ta[sc + c][sr] = tmp[c];
        }
        // stage B (transposed into [k][n])
        {
            float tmp[16];
            if (n0 + wm < Brows) {
                const float* src = B + (n0 + wm) * DM + k0 + wc0;
                #pragma unroll
                for (int c4 = 0; c4 < 4; ++c4) {
                    f32x4 v = *(const f32x4*)(src + c4 * 4);
                    tmp[c4*4+0]=v[0]; tmp[c4*4+1]=v[1]; tmp[c4*4+2]=v[2]; tmp[c4*4+3]=v[3];
                }
            } else {
                #pragma unroll
                for (int c = 0; c < 16; ++c) tmp[c] = 0.f;
            }
            #pragma unroll
            for (int c = 0; c < 16; ++c) Wb[wc0 + c][wm] = tmp[c];
        }
        __syncthreads();

        #pragma unroll 8
        for (int k = 0; k < 32; ++k) {
            f32x4 a4 = *(const f32x4*)&Ta[k][tr * 4];
            f32x4 b0 = *(const f32x4*)&Wb[k][tm * 8];
            f32x4 b1 = *(const f32x4*)&Wb[k][tm * 8 + 4];
            #pragma unroll
            for (int i = 0; i < 4; ++i) {
                #pragma unroll
                for (int j = 0; j < 4; ++j) {
                    acc[i][j]     += a4[i] * b0[j];
                    acc[i][j + 4] += a4[i] * b1[j];
                }
            }
        }
        __syncthreads();
    }

    #pragma unroll
    for (int i = 0; i < 4; ++i) {
        int row = row0 + tr * 4 + i;
        if (row >= TROWS) continue;
        #pragma unroll
        for (int j = 0; j < 8; ++j) {
            int col = n0 + tm * 8 + j;
            float v = acc[i][j];
            if (row == biasRow) v += bias[col];
            C[row * ldC + col] = v;
        }
    }
}

// ---------------------------------------------------------------------------
// M_bf[128][4096] (bf16) = U (113x1024, zero-padded to 128) * W_out (1024x4096)
// BM=128 (all v), BN=32 (blockIdx.x), BK=32. fp32 compute, bf16 store.
// ---------------------------------------------------------------------------
__global__ __launch_bounds__(256) void k_gemm_m(
    unsigned short* __restrict__ Mb,
    const float* __restrict__ U,
    const float* __restrict__ Wo)
{
    __shared__ float Ua[32][132];   // [k][v]
    __shared__ float Wb2[32][36];   // [k][m]

    const int tid = threadIdx.x;
    const int m0 = blockIdx.x * 32;
    const int tv = tid >> 3, tm = tid & 7;

    const int sv = tid >> 1, skh = (tid & 1) * 16;    // U-stage
    const int swr = tid >> 3, swc = (tid & 7) * 4;    // W-stage

    float acc[4][4];
    #pragma unroll
    for (int i = 0; i < 4; ++i)
        #pragma unroll
        for (int j = 0; j < 4; ++j) acc[i][j] = 0.f;

    for (int k0 = 0; k0 < DM; k0 += 32) {
        {
            float tmp[16];
            if (sv < PMOD) {
                const float* src = U + sv * DM + k0 + skh;
                #pragma unroll
                for (int c4 = 0; c4 < 4; ++c4) {
                    f32x4 v = *(const f32x4*)(src + c4 * 4);
                    tmp[c4*4+0]=v[0]; tmp[c4*4+1]=v[1]; tmp[c4*4+2]=v[2]; tmp[c4*4+3]=v[3];
                }
            } else {
                #pragma unroll
                for (int c = 0; c < 16; ++c) tmp[c] = 0.f;
            }
            #pragma unroll
            for (int c = 0; c < 16; ++c) Ua[skh + c][sv] = tmp[c];
        }
        {
            f32x4 v = *(const f32x4*)(Wo + (k0 + swr) * DMLP + m0 + swc);
            *(f32x4*)&Wb2[swr][swc] = v;
        }
        __syncthreads();

        #pragma unroll 8
        for (int k = 0; k < 32; ++k) {
            f32x4 a4 = *(const f32x4*)&Ua[k][tv * 4];
            f32x4 b4 = *(const f32x4*)&Wb2[k][tm * 4];
            #pragma unroll
            for (int i = 0; i < 4; ++i)
                #pragma unroll
                for (int j = 0; j < 4; ++j)
                    acc[i][j] += a4[i] * b4[j];
        }
        __syncthreads();
    }

    #pragma unroll
    for (int i = 0; i < 4; ++i) {
        int v = tv * 4 + i;
        ushort4v pk;
        #pragma unroll
        for (int j = 0; j < 4; ++j) pk[j] = (unsigned short)f2bf(acc[i][j]);
        *(ushort4v*)&Mb[v * DMLP + m0 + tm * 4] = pk;
    }
}

// ---------------------------------------------------------------------------
// Pair GEMM (MFMA bf16): for p in [0,12769): a=p/113, b=p%113
//   h[m] = relu(H[226][m] + H[a][m] + H[113+b][m])   (computed on the fly, bf16)
//   LT[p][v] = sum_m h[m]*M[v][m] + L[a][v] + L[113+b][v] + L[226][v] + L[227][v]
// BM=64 rows/block (200 blocks), BN=128, BK=64. 4 waves, each 32x64.
// ---------------------------------------------------------------------------
__global__ __launch_bounds__(256) void k_pair_gemm(
    float* __restrict__ LT,
    const float* __restrict__ H,
    const unsigned short* __restrict__ Mb,
    const float* __restrict__ L)
{
    __shared__ short hA[64 * 72];    // [row][k] bf16, row stride 72
    __shared__ short mB[128 * 72];   // [v][k]  bf16, row stride 72

    const int tid = threadIdx.x;
    const int pbase = blockIdx.x * 64;

    // h staging: row sr, k-quarter sq (16 cols)
    const int sr = tid >> 2, sq = (tid & 3) * 16;
    const unsigned int p_r = (unsigned)(pbase + sr);
    const unsigned int a_r = p_r / 113u;
    const unsigned int b_r = p_r - a_r * 113u;
    const float* pA = H + a_r * DMLP;
    const float* pB = H + (PMOD + b_r) * DMLP;
    const float* pC = H + 226 * DMLP;

    // M staging: row mv, k-half mk (32 cols)
    const int mv = tid >> 1, mk = (tid & 1) * 32;
    const unsigned short* pM = Mb + mv * DMLP + mk;

    const int lane = tid & 63, w = tid >> 6;
    const int wr = w >> 1, wc = w & 1;
    const int lr = lane & 15, lg = lane >> 4;

    f32x4 acc[2][4];
    #pragma unroll
    for (int i = 0; i < 2; ++i)
        #pragma unroll
        for (int j = 0; j < 4; ++j) acc[i][j] = 0.f;

    for (int k0 = 0; k0 < DMLP; k0 += 64) {
        // stage h tile (compute + relu + bf16)
        {
            short8 u0, u1;
            #pragma unroll
            for (int c4 = 0; c4 < 4; ++c4) {
                f32x4 va = *(const f32x4*)(pA + k0 + sq + c4 * 4);
                f32x4 vb = *(const f32x4*)(pB + k0 + sq + c4 * 4);
                f32x4 vh = *(const f32x4*)(pC + k0 + sq + c4 * 4);
                #pragma unroll
                for (int e = 0; e < 4; ++e) {
                    float hv = fmaxf(va[e] + vb[e] + vh[e], 0.f);
                    short bv = f2bf(hv);
                    if (c4 < 2) u0[c4 * 4 + e] = bv;
                    else        u1[(c4 - 2) * 4 + e] = bv;
                }
            }
            *(short8*)&hA[sr * 72 + sq] = u0;
            *(short8*)&hA[sr * 72 + sq + 8] = u1;
        }
        // stage M tile (copy)
        {
            const short8* s = (const short8*)(pM + k0);
            short8 t0 = s[0], t1 = s[1], t2 = s[2], t3 = s[3];
            *(short8*)&mB[mv * 72 + mk] = t0;
            *(short8*)&mB[mv * 72 + mk + 8] = t1;
            *(short8*)&mB[mv * 72 + mk + 16] = t2;
            *(short8*)&mB[mv * 72 + mk + 24] = t3;
        }
        __syncthreads();

        #pragma unroll
        for (int ks = 0; ks < 2; ++ks) {
            short8 af[2], bf[4];
            #pragma unroll
            for (int i = 0; i < 2; ++i)
                af[i] = *(const short8*)&hA[(wr * 32 + i * 16 + lr) * 72 + ks * 32 + lg * 8];
            #pragma unroll
            for (int j = 0; j < 4; ++j)
                bf[j] = *(const short8*)&mB[(wc * 64 + j * 16 + lr) * 72 + ks * 32 + lg * 8];
            #pragma unroll
            for (int i = 0; i < 2; ++i)
                #pragma unroll
                for (int j = 0; j < 4; ++j)
                    acc[i][j] = __builtin_amdgcn_mfma_f32_16x16x32_bf16(af[i], bf[j], acc[i][j], 0, 0, 0);
        }
        __syncthreads();
    }

    // epilogue: add the linear (non-MLP) logit terms and store
    #pragma unroll
    for (int i = 0; i < 2; ++i) {
        #pragma unroll
        for (int q = 0; q < 4; ++q) {
            int p = pbase + wr * 32 + i * 16 + lg * 4 + q;
            if (p >= NPAIR) continue;
            unsigned int pa = (unsigned)p / 113u;
            unsigned int pb = (unsigned)p - pa * 113u;
            const float* La = L + pa * 128;
            const float* Lb = L + (PMOD + pb) * 128;
            const float* Lc = L + 226 * 128;
            const float* Ld = L + 227 * 128;
            float* dst = LT + (size_t)p * 128;
            #pragma unroll
            for (int j = 0; j < 4; ++j) {
                int col = wc * 64 + j * 16 + lr;
                dst[col] = acc[i][j][q] + La[col] + Lb[col] + Lc[col] + Ld[col];
            }
        }
    }
}

// ---------------------------------------------------------------------------
// Gather: out[i, v] = LT[a[i]*113 + b[i], v]
// ---------------------------------------------------------------------------
__global__ __launch_bounds__(256) void k_gather(
    float* __restrict__ out, const float* __restrict__ LT,
    const int* __restrict__ a, const int* __restrict__ b)
{
    int g = blockIdx.x * 256 + threadIdx.x;
    if (g >= NBATCH * PMOD) return;
    unsigned int i = (unsigned)g / 113u;
    unsigned int v = (unsigned)g - i * 113u;
    unsigned int pair = (unsigned)a[i] * 113u + (unsigned)b[i];
    out[g] = LT[(size_t)pair * 128 + v];
}

// ---------------------------------------------------------------------------
extern "C" void kernel_launch(void* const* d_in, const int* in_sizes, int n_in,
                              void* d_out, int out_size, void* d_ws, size_t ws_size,
                              hipStream_t stream)
{
    const int*   a   = (const int*)d_in[0];
    const int*   b   = (const int*)d_in[1];
    const float* E   = (const float*)d_in[2];   // (114, 1024)
    const float* pos = (const float*)d_in[3];   // (3, 1024)
    const float* Wi  = (const float*)d_in[4];   // (4096, 1024)
    const float* bi  = (const float*)d_in[5];   // (4096,)
    const float* Wo  = (const float*)d_in[6];   // (1024, 4096)
    const float* bo  = (const float*)d_in[7];   // (1024,)
    const float* U   = (const float*)d_in[8];   // (113, 1024)
    float* out = (float*)d_out;

    float* T  = (float*)d_ws;                 // 228*1024
    float* H  = T + TROWS * DM;               // 228*4096
    float* L  = H + TROWS * DMLP;             // 228*128
    float* LT = L + TROWS * 128;              // 12800*128
    unsigned short* Mb = (unsigned short*)(LT + 12800 * 128);  // 128*4096 bf16

    k_tables<<<228, 256, 0, stream>>>(T, E, pos, bo);
    k_gemm_nt<<<dim3(32, 4), 256, 0, stream>>>(H, DMLP, T, Wi, DMLP, bi, 226);
    k_gemm_nt<<<dim3(1, 4), 256, 0, stream>>>(L, 128, T, U, PMOD, nullptr, -1);
    k_gemm_m<<<128, 256, 0, stream>>>(Mb, U, Wo);
    k_pair_gemm<<<200, 256, 0, stream>>>(LT, H, Mb, L);
    k_gather<<<(NBATCH * PMOD + 255) / 256, 256, 0, stream>>>(out, LT, a, b);

    (void)in_sizes; (void)n_in; (void)out_size; (void)ws_size;
}

// Round 2
// 352.003 us; speedup vs baseline: 1.6327x; 1.6327x over previous
//
#include <hip/hip_runtime.h>

typedef __attribute__((ext_vector_type(4))) float f32x4;
typedef __attribute__((ext_vector_type(8))) short short8;
typedef __attribute__((ext_vector_type(4))) unsigned short ushort4v;

#define PMOD 113
#define NPAIR 12769
#define DM 1024
#define DMLP 4096
#define NBATCH 16384
#define SQRT3_2 0.86602540378443865f
#define CSTEP 6.1359231515425649e-3f   // 2*pi/1024

__device__ __forceinline__ short f2bf(float x) {
    unsigned int u = __builtin_bit_cast(unsigned int, x);
    u += 0x7FFFu + ((u >> 16) & 1u);
    return (short)(u >> 16);
}

// ---------------------------------------------------------------------------
// F[1024][1024]: folded real-DFT basis.
//   k<=512 : F[f][k] = cos(2*pi*f*k/1024)
//   k>512  : F[f][k] = sin(2*pi*f*(k-512)/1024)
// ---------------------------------------------------------------------------
__global__ __launch_bounds__(256) void k_fmat(float* __restrict__ F)
{
    const int f = blockIdx.x, tid = threadIdx.x;
    for (int k = tid; k < DM; k += 256) {
        float v;
        if (k <= 512) v = cosf((float)((f * k) & 1023) * CSTEP);
        else          v = sinf((float)((f * (k - 512)) & 1023) * CSTEP);
        F[f * DM + k] = v;
    }
}

// ---------------------------------------------------------------------------
// V2[227][1024]: folded coefficients so that T[t][f] (DFT part) = V2[t] . F[f]
//   t<113   : vc = E[t],            vs = 0
//   113..225: vc = -1/2 E[t-113],   vs = sqrt3/2 E[t-113]
//   226     : vc = p0 - p1/2 - e2/2, vs = sqrt3/2 (p1 - e2), e2 = E[113]+p2
// fold: V2[k=0]=vc[0]; V2[k in 1..511]=vc[k]+vc[1024-k]; V2[512]=vc[512];
//       V2[512+d]=vs[d]-vs[1024-d] (d in 1..511)
// ---------------------------------------------------------------------------
__global__ __launch_bounds__(256) void k_v2(
    float* __restrict__ V2, const float* __restrict__ E,
    const float* __restrict__ pos)
{
    const int t = blockIdx.x, tid = threadIdx.x;
    __shared__ float vc[DM];
    __shared__ float vs[DM];

    if (t < PMOD) {
        const float* e = E + t * DM;
        for (int d = tid; d < DM; d += 256) { vc[d] = e[d]; vs[d] = 0.f; }
    } else if (t < 2 * PMOD) {
        const float* e = E + (t - PMOD) * DM;
        for (int d = tid; d < DM; d += 256) {
            float x = e[d];
            vc[d] = -0.5f * x;
            vs[d] = SQRT3_2 * x;
        }
    } else {
        const float* e2 = E + PMOD * DM;
        for (int d = tid; d < DM; d += 256) {
            float e2v = e2[d] + pos[2 * DM + d];
            vc[d] = pos[d] - 0.5f * pos[DM + d] - 0.5f * e2v;
            vs[d] = SQRT3_2 * (pos[DM + d] - e2v);
        }
    }
    __syncthreads();

    for (int k = tid; k < DM; k += 256) {
        float o;
        if (k == 0)        o = vc[0];
        else if (k < 512)  o = vc[k] + vc[1024 - k];
        else if (k == 512) o = vc[512];
        else               o = vs[k - 512] - vs[1536 - k];
        V2[t * DM + k] = o;
    }
}

// ---------------------------------------------------------------------------
// Shared fp32 NT GEMM, BM=64, BN=64, BK=32, 256 threads, 4x4 acc/thread.
// MODE 0 (T-gemm):  C1[row][f] = V2 . F  (+ e2 on row226, row227 := bo)
// MODE 1 (HL-gemm): N=4224: cols <4096 -> H (B=Wi, +bias on row226),
//                   cols >=4096 -> L (B=U zero-padded past 113 rows)
// ---------------------------------------------------------------------------
template<int MODE>
__global__ __launch_bounds__(256) void k_gemm(
    float* __restrict__ C1, float* __restrict__ C2,
    const float* __restrict__ A, int Arows,
    const float* __restrict__ B1, const float* __restrict__ B2,
    const float* __restrict__ bias,
    const float* __restrict__ E, const float* __restrict__ pos,
    const float* __restrict__ bo)
{
    __shared__ float Ta[32][68];   // [k][row]
    __shared__ float Wb[32][68];   // [k][n]

    const int tid = threadIdx.x;
    const int n0 = blockIdx.x * 64;
    const int row0 = blockIdx.y * 64;
    const int sr = tid >> 2, sc = (tid & 3) * 8;
    const int tr = tid >> 4, tc = tid & 15;

    const float* aptr = (row0 + sr < Arows) ? (A + (row0 + sr) * DM) : nullptr;
    const float* bptr;
    {
        int n = n0 + sr;
        if (MODE == 0) bptr = B1 + n * DM;
        else if (n < 4096) bptr = B1 + n * DM;
        else { int u = n - 4096; bptr = (u < PMOD) ? (B2 + u * DM) : nullptr; }
    }

    float acc[4][4];
    #pragma unroll
    for (int i = 0; i < 4; ++i)
        #pragma unroll
        for (int j = 0; j < 4; ++j) acc[i][j] = 0.f;

    for (int k0 = 0; k0 < DM; k0 += 32) {
        float ta[8], tb[8];
        if (aptr) {
            f32x4 v0 = *(const f32x4*)(aptr + k0 + sc);
            f32x4 v1 = *(const f32x4*)(aptr + k0 + sc + 4);
            ta[0]=v0[0]; ta[1]=v0[1]; ta[2]=v0[2]; ta[3]=v0[3];
            ta[4]=v1[0]; ta[5]=v1[1]; ta[6]=v1[2]; ta[7]=v1[3];
        } else {
            #pragma unroll
            for (int c = 0; c < 8; ++c) ta[c] = 0.f;
        }
        if (bptr) {
            f32x4 v0 = *(const f32x4*)(bptr + k0 + sc);
            f32x4 v1 = *(const f32x4*)(bptr + k0 + sc + 4);
            tb[0]=v0[0]; tb[1]=v0[1]; tb[2]=v0[2]; tb[3]=v0[3];
            tb[4]=v1[0]; tb[5]=v1[1]; tb[6]=v1[2]; tb[7]=v1[3];
        } else {
            #pragma unroll
            for (int c = 0; c < 8; ++c) tb[c] = 0.f;
        }
        if (k0) __syncthreads();
        #pragma unroll
        for (int c = 0; c < 8; ++c) { Ta[sc + c][sr] = ta[c]; Wb[sc + c][sr] = tb[c]; }
        __syncthreads();

        #pragma unroll 8
        for (int k = 0; k < 32; ++k) {
            f32x4 a4 = *(const f32x4*)&Ta[k][tr * 4];
            f32x4 b4 = *(const f32x4*)&Wb[k][tc * 4];
            #pragma unroll
            for (int i = 0; i < 4; ++i)
                #pragma unroll
                for (int j = 0; j < 4; ++j)
                    acc[i][j] += a4[i] * b4[j];
        }
    }

    #pragma unroll
    for (int i = 0; i < 4; ++i) {
        int row = row0 + tr * 4 + i;
        if (row >= 228) continue;
        f32x4 v;
        #pragma unroll
        for (int j = 0; j < 4; ++j) v[j] = acc[i][j];

        if (MODE == 0) {
            int col0 = n0 + tc * 4;
            if (row == 226) {
                #pragma unroll
                for (int j = 0; j < 4; ++j)
                    v[j] += E[PMOD * DM + col0 + j] + pos[2 * DM + col0 + j];
            }
            if (row == 227) {
                #pragma unroll
                for (int j = 0; j < 4; ++j) v[j] = bo[col0 + j];
            }
            *(f32x4*)&C1[row * DM + col0] = v;
        } else {
            if (n0 < 4096) {
                int col0 = n0 + tc * 4;
                if (row == 226) {
                    #pragma unroll
                    for (int j = 0; j < 4; ++j) v[j] += bias[col0 + j];
                }
                *(f32x4*)&C1[row * DMLP + col0] = v;
            } else {
                int col0 = n0 - 4096 + tc * 4;
                *(f32x4*)&C2[row * 128 + col0] = v;
            }
        }
    }
}

// ---------------------------------------------------------------------------
// Mb[128][4096] bf16 = U(113x1024, zero-pad to 128) * Wo(1024x4096)
// BM=64(v), BN=32(m), grid (128,2)
// ---------------------------------------------------------------------------
__global__ __launch_bounds__(256) void k_gemm_m(
    unsigned short* __restrict__ Mb,
    const float* __restrict__ U,
    const float* __restrict__ Wo)
{
    __shared__ float Ua[32][68];
    __shared__ float Wb2[32][36];

    const int tid = threadIdx.x;
    const int m0 = blockIdx.x * 32;
    const int v0 = blockIdx.y * 64;
    const int sr = tid >> 2, sc = (tid & 3) * 8;
    const int swr = tid >> 3, swc = (tid & 7) * 4;
    const int tv = tid >> 3, tc = tid & 7;

    const float* uptr = (v0 + sr < PMOD) ? (U + (v0 + sr) * DM) : nullptr;

    float acc[2][4];
    #pragma unroll
    for (int i = 0; i < 2; ++i)
        #pragma unroll
        for (int j = 0; j < 4; ++j) acc[i][j] = 0.f;

    for (int k0 = 0; k0 < DM; k0 += 32) {
        float ua[8];
        if (uptr) {
            f32x4 v0v = *(const f32x4*)(uptr + k0 + sc);
            f32x4 v1v = *(const f32x4*)(uptr + k0 + sc + 4);
            ua[0]=v0v[0]; ua[1]=v0v[1]; ua[2]=v0v[2]; ua[3]=v0v[3];
            ua[4]=v1v[0]; ua[5]=v1v[1]; ua[6]=v1v[2]; ua[7]=v1v[3];
        } else {
            #pragma unroll
            for (int c = 0; c < 8; ++c) ua[c] = 0.f;
        }
        f32x4 wv = *(const f32x4*)(Wo + (k0 + swr) * DMLP + m0 + swc);
        if (k0) __syncthreads();
        #pragma unroll
        for (int c = 0; c < 8; ++c) Ua[sc + c][sr] = ua[c];
        *(f32x4*)&Wb2[swr][swc] = wv;
        __syncthreads();

        #pragma unroll 8
        for (int k = 0; k < 32; ++k) {
            float a0 = Ua[k][tv * 2], a1 = Ua[k][tv * 2 + 1];
            f32x4 b4 = *(const f32x4*)&Wb2[k][tc * 4];
            #pragma unroll
            for (int j = 0; j < 4; ++j) {
                acc[0][j] += a0 * b4[j];
                acc[1][j] += a1 * b4[j];
            }
        }
    }

    #pragma unroll
    for (int i = 0; i < 2; ++i) {
        int v = v0 + tv * 2 + i;
        ushort4v pk;
        #pragma unroll
        for (int j = 0; j < 4; ++j) pk[j] = (unsigned short)f2bf(acc[i][j]);
        *(ushort4v*)&Mb[v * DMLP + m0 + tc * 4] = pk;
    }
}

// ---------------------------------------------------------------------------
// Fold const rows: H[a] += H[226]; L[a] += L[226] + L[227]  (a < 113)
// ---------------------------------------------------------------------------
__global__ __launch_bounds__(256) void k_fold(float* __restrict__ H, float* __restrict__ L)
{
    const int a = blockIdx.x, tid = threadIdx.x;
    for (int i = tid * 4; i < DMLP; i += 1024) {
        f32x4 v = *(f32x4*)&H[a * DMLP + i];
        v += *(const f32x4*)&H[226 * DMLP + i];
        *(f32x4*)&H[a * DMLP + i] = v;
    }
    if (tid < 32) {
        int i = tid * 4;
        f32x4 v = *(f32x4*)&L[a * 128 + i];
        v += *(const f32x4*)&L[226 * 128 + i];
        v += *(const f32x4*)&L[227 * 128 + i];
        *(f32x4*)&L[a * 128 + i] = v;
    }
}

// ---------------------------------------------------------------------------
// Pair GEMM (MFMA bf16): block = (a, b-tile of 64). rows: b = b0 + sr.
//   h[m] = relu(H[a][m] + H[113+b][m])          (const folded into H[a])
//   LT[a*113+b][v] = sum_m h[m]*Mb[v][m] + L[a][v] + L[113+b][v]
// ---------------------------------------------------------------------------
__global__ __launch_bounds__(256) void k_pair_gemm(
    float* __restrict__ LT,
    const float* __restrict__ H,
    const unsigned short* __restrict__ Mb,
    const float* __restrict__ L)
{
    __shared__ short hA[64 * 72];
    __shared__ short mB[128 * 72];

    const int tid = threadIdx.x;
    const int a = blockIdx.x;
    const int b0 = blockIdx.y ? 49 : 0;

    const int sr = tid >> 2, sq = (tid & 3) * 16;
    const float* pA = H + a * DMLP;
    const float* pB = H + (PMOD + b0 + sr) * DMLP;

    const int mv = tid >> 1, mk = (tid & 1) * 32;
    const unsigned short* pM = Mb + mv * DMLP + mk;

    const int lane = tid & 63, w = tid >> 6;
    const int wr = w >> 1, wc = w & 1;
    const int lr = lane & 15, lg = lane >> 4;

    f32x4 acc[2][4];
    #pragma unroll
    for (int i = 0; i < 2; ++i)
        #pragma unroll
        for (int j = 0; j < 4; ++j) acc[i][j] = 0.f;

    for (int k0 = 0; k0 < DMLP; k0 += 64) {
        {
            short8 u0, u1;
            #pragma unroll
            for (int c4 = 0; c4 < 4; ++c4) {
                f32x4 va = *(const f32x4*)(pA + k0 + sq + c4 * 4);
                f32x4 vb = *(const f32x4*)(pB + k0 + sq + c4 * 4);
                #pragma unroll
                for (int e = 0; e < 4; ++e) {
                    float hv = fmaxf(va[e] + vb[e], 0.f);
                    short bv = f2bf(hv);
                    if (c4 < 2) u0[c4 * 4 + e] = bv;
                    else        u1[(c4 - 2) * 4 + e] = bv;
                }
            }
            const short8* s = (const short8*)(pM + k0);
            short8 t0 = s[0], t1 = s[1], t2 = s[2], t3 = s[3];
            if (k0) __syncthreads();
            *(short8*)&hA[sr * 72 + sq] = u0;
            *(short8*)&hA[sr * 72 + sq + 8] = u1;
            *(short8*)&mB[mv * 72 + mk] = t0;
            *(short8*)&mB[mv * 72 + mk + 8] = t1;
            *(short8*)&mB[mv * 72 + mk + 16] = t2;
            *(short8*)&mB[mv * 72 + mk + 24] = t3;
        }
        __syncthreads();

        #pragma unroll
        for (int ks = 0; ks < 2; ++ks) {
            short8 af[2], bf[4];
            #pragma unroll
            for (int i = 0; i < 2; ++i)
                af[i] = *(const short8*)&hA[(wr * 32 + i * 16 + lr) * 72 + ks * 32 + lg * 8];
            #pragma unroll
            for (int j = 0; j < 4; ++j)
                bf[j] = *(const short8*)&mB[(wc * 64 + j * 16 + lr) * 72 + ks * 32 + lg * 8];
            #pragma unroll
            for (int i = 0; i < 2; ++i)
                #pragma unroll
                for (int j = 0; j < 4; ++j)
                    acc[i][j] = __builtin_amdgcn_mfma_f32_16x16x32_bf16(af[i], bf[j], acc[i][j], 0, 0, 0);
        }
    }

    const float* La = L + a * 128;
    #pragma unroll
    for (int i = 0; i < 2; ++i) {
        #pragma unroll
        for (int q = 0; q < 4; ++q) {
            int b = b0 + wr * 32 + i * 16 + lg * 4 + q;
            int p = a * PMOD + b;
            const float* Lb = L + (PMOD + b) * 128;
            float* dst = LT + (size_t)p * 128;
            #pragma unroll
            for (int j = 0; j < 4; ++j) {
                int col = wc * 64 + j * 16 + lr;
                dst[col] = acc[i][j][q] + La[col] + Lb[col];
            }
        }
    }
}

// ---------------------------------------------------------------------------
__global__ __launch_bounds__(256) void k_gather(
    float* __restrict__ out, const float* __restrict__ LT,
    const int* __restrict__ a, const int* __restrict__ b)
{
    int g = blockIdx.x * 256 + threadIdx.x;
    if (g >= NBATCH * PMOD) return;
    unsigned int i = (unsigned)g / 113u;
    unsigned int v = (unsigned)g - i * 113u;
    unsigned int pair = (unsigned)a[i] * 113u + (unsigned)b[i];
    out[g] = LT[(size_t)pair * 128 + v];
}

// ---------------------------------------------------------------------------
extern "C" void kernel_launch(void* const* d_in, const int* in_sizes, int n_in,
                              void* d_out, int out_size, void* d_ws, size_t ws_size,
                              hipStream_t stream)
{
    const int*   a   = (const int*)d_in[0];
    const int*   b   = (const int*)d_in[1];
    const float* E   = (const float*)d_in[2];
    const float* pos = (const float*)d_in[3];
    const float* Wi  = (const float*)d_in[4];
    const float* bi  = (const float*)d_in[5];
    const float* Wo  = (const float*)d_in[6];
    const float* bo  = (const float*)d_in[7];
    const float* U   = (const float*)d_in[8];
    float* out = (float*)d_out;

    float* V2 = (float*)d_ws;                  // 228*1024
    float* F  = V2 + 228 * DM;                 // 1024*1024
    float* T  = F + DM * DM;                   // 228*1024
    float* H  = T + 228 * DM;                  // 228*4096
    float* L  = H + 228 * DMLP;                // 228*128
    float* LT = L + 228 * 128;                 // 12800*128
    unsigned short* Mb = (unsigned short*)(LT + 12800 * 128);  // 128*4096 bf16

    k_fmat<<<DM, 256, 0, stream>>>(F);
    k_v2<<<227, 256, 0, stream>>>(V2, E, pos);
    k_gemm_m<<<dim3(128, 2), 256, 0, stream>>>(Mb, U, Wo);
    k_gemm<0><<<dim3(16, 4), 256, 0, stream>>>(T, nullptr, V2, 227, F, nullptr,
                                               nullptr, E, pos, bo);
    k_gemm<1><<<dim3(66, 4), 256, 0, stream>>>(H, L, T, 228, Wi, U,
                                               bi, nullptr, nullptr, nullptr);
    k_fold<<<PMOD, 256, 0, stream>>>(H, L);
    k_pair_gemm<<<dim3(PMOD, 2), 256, 0, stream>>>(LT, H, Mb, L);
    k_gather<<<(NBATCH * PMOD + 255) / 256, 256, 0, stream>>>(out, LT, a, b);

    (void)in_sizes; (void)n_in; (void)out_size; (void)ws_size;
}

// Round 3
// 315.732 us; speedup vs baseline: 1.8202x; 1.1149x over previous
//
#include <hip/hip_runtime.h>

typedef __attribute__((ext_vector_type(4))) float f32x4;
typedef __attribute__((ext_vector_type(8))) short short8;
typedef __attribute__((ext_vector_type(4))) unsigned short ushort4v;

#define PMOD 113
#define DM 1024
#define DMLP 4096
#define NBATCH 16384
#define SQRT3_2 0.86602540378443865f
#define CSTEP 6.1359231515425649e-3f   // 2*pi/1024

__device__ __forceinline__ short f2bf(float x) {
    unsigned int u = __builtin_bit_cast(unsigned int, x);
    u += 0x7FFFu + ((u >> 16) & 1u);
    return (short)(u >> 16);
}

// ---------------------------------------------------------------------------
// F[1024][1024]: folded real-DFT basis.
//   k<=512 : F[f][k] = cos(2*pi*f*k/1024)
//   k>512  : F[f][k] = sin(2*pi*f*(k-512)/1024)
// ---------------------------------------------------------------------------
__global__ __launch_bounds__(256) void k_fmat(float* __restrict__ F)
{
    const int f = blockIdx.x, tid = threadIdx.x;
    for (int k = tid; k < DM; k += 256) {
        float v;
        if (k <= 512) v = cosf((float)((f * k) & 1023) * CSTEP);
        else          v = sinf((float)((f * (k - 512)) & 1023) * CSTEP);
        F[f * DM + k] = v;
    }
}

// ---------------------------------------------------------------------------
// V2[226][1024]: folded DFT coefficients. Const row is folded INTO rows <113:
//   t<113   : vc = E[t] + p0 - p1/2 - e2/2, vs = sqrt3/2 (p1 - e2)
//   113..225: vc = -1/2 E[t-113],           vs = sqrt3/2 E[t-113]
// (e2 = E[113]+pos2; the raw e2 vector itself is added post-DFT in k_gemm<0>)
// fold: V2[0]=vc[0]; V2[k]=vc[k]+vc[1024-k] (1<=k<512); V2[512]=vc[512];
//       V2[512+d]=vs[d]-vs[1024-d] (d in 1..511)
// ---------------------------------------------------------------------------
__global__ __launch_bounds__(256) void k_v2(
    float* __restrict__ V2, const float* __restrict__ E,
    const float* __restrict__ pos)
{
    const int t = blockIdx.x, tid = threadIdx.x;
    __shared__ float vc[DM];
    __shared__ float vs[DM];

    if (t < PMOD) {
        const float* e = E + t * DM;
        const float* e2 = E + PMOD * DM;
        for (int d = tid; d < DM; d += 256) {
            float e2v = e2[d] + pos[2 * DM + d];
            vc[d] = e[d] + pos[d] - 0.5f * pos[DM + d] - 0.5f * e2v;
            vs[d] = SQRT3_2 * (pos[DM + d] - e2v);
        }
    } else {
        const float* e = E + (t - PMOD) * DM;
        for (int d = tid; d < DM; d += 256) {
            float x = e[d];
            vc[d] = -0.5f * x;
            vs[d] = SQRT3_2 * x;
        }
    }
    __syncthreads();

    for (int k = tid; k < DM; k += 256) {
        float o;
        if (k == 0)        o = vc[0];
        else if (k < 512)  o = vc[k] + vc[1024 - k];
        else if (k == 512) o = vc[512];
        else               o = vs[k - 512] - vs[1536 - k];
        V2[t * DM + k] = o;
    }
}

// ---------------------------------------------------------------------------
// fp32 NT GEMM, BM=64, BN=64, BK=32, split-K over blockIdx.z, atomicAdd out.
// Output buffers must be pre-zeroed.
// MODE 0 (T-gemm):  T[row][f] += V2 . F; slice0: rows<113 += e2, row227 += bo
// MODE 1 (HL-gemm): N=4224: cols<4096 -> H (B=Wi, slice0 rows<113 += bi),
//                   cols>=4096 -> L (B=U zero-padded past 113 rows)
// ---------------------------------------------------------------------------
template<int MODE>
__global__ __launch_bounds__(256) void k_gemm(
    float* __restrict__ C1, float* __restrict__ C2,
    const float* __restrict__ A, int Arows,
    const float* __restrict__ B1, const float* __restrict__ B2,
    const float* __restrict__ bias,
    const float* __restrict__ E, const float* __restrict__ pos,
    const float* __restrict__ bo, int kslice)
{
    __shared__ float Ta[32][68];   // [k][row]
    __shared__ float Wb[32][68];   // [k][n]

    const int tid = threadIdx.x;
    const int n0 = blockIdx.x * 64;
    const int row0 = blockIdx.y * 64;
    const int kbeg = blockIdx.z * kslice;
    const bool slice0 = (blockIdx.z == 0);
    const int sr = tid >> 2, sc = (tid & 3) * 8;
    const int tr = tid >> 4, tc = tid & 15;

    const float* aptr = (row0 + sr < Arows) ? (A + (row0 + sr) * DM) : nullptr;
    const float* bptr;
    {
        int n = n0 + sr;
        if (MODE == 0) bptr = B1 + n * DM;
        else if (n < 4096) bptr = B1 + n * DM;
        else { int u = n - 4096; bptr = (u < PMOD) ? (B2 + u * DM) : nullptr; }
    }

    float acc[4][4];
    #pragma unroll
    for (int i = 0; i < 4; ++i)
        #pragma unroll
        for (int j = 0; j < 4; ++j) acc[i][j] = 0.f;

    for (int k0 = kbeg; k0 < kbeg + kslice; k0 += 32) {
        float ta[8], tb[8];
        if (aptr) {
            f32x4 v0 = *(const f32x4*)(aptr + k0 + sc);
            f32x4 v1 = *(const f32x4*)(aptr + k0 + sc + 4);
            ta[0]=v0[0]; ta[1]=v0[1]; ta[2]=v0[2]; ta[3]=v0[3];
            ta[4]=v1[0]; ta[5]=v1[1]; ta[6]=v1[2]; ta[7]=v1[3];
        } else {
            #pragma unroll
            for (int c = 0; c < 8; ++c) ta[c] = 0.f;
        }
        if (bptr) {
            f32x4 v0 = *(const f32x4*)(bptr + k0 + sc);
            f32x4 v1 = *(const f32x4*)(bptr + k0 + sc + 4);
            tb[0]=v0[0]; tb[1]=v0[1]; tb[2]=v0[2]; tb[3]=v0[3];
            tb[4]=v1[0]; tb[5]=v1[1]; tb[6]=v1[2]; tb[7]=v1[3];
        } else {
            #pragma unroll
            for (int c = 0; c < 8; ++c) tb[c] = 0.f;
        }
        if (k0 != kbeg) __syncthreads();
        #pragma unroll
        for (int c = 0; c < 8; ++c) { Ta[sc + c][sr] = ta[c]; Wb[sc + c][sr] = tb[c]; }
        __syncthreads();

        #pragma unroll 8
        for (int k = 0; k < 32; ++k) {
            f32x4 a4 = *(const f32x4*)&Ta[k][tr * 4];
            f32x4 b4 = *(const f32x4*)&Wb[k][tc * 4];
            #pragma unroll
            for (int i = 0; i < 4; ++i)
                #pragma unroll
                for (int j = 0; j < 4; ++j)
                    acc[i][j] += a4[i] * b4[j];
        }
    }

    #pragma unroll
    for (int i = 0; i < 4; ++i) {
        int row = row0 + tr * 4 + i;
        if (row >= 228) continue;

        if (MODE == 0) {
            int col0 = n0 + tc * 4;
            #pragma unroll
            for (int j = 0; j < 4; ++j) {
                float v = acc[i][j];
                if (slice0) {
                    if (row < PMOD)
                        v += E[PMOD * DM + col0 + j] + pos[2 * DM + col0 + j];
                    if (row == 227) v += bo[col0 + j];
                }
                atomicAdd(&C1[row * DM + col0 + j], v);
            }
        } else {
            if (n0 < 4096) {
                int col0 = n0 + tc * 4;
                #pragma unroll
                for (int j = 0; j < 4; ++j) {
                    float v = acc[i][j];
                    if (slice0 && row < PMOD) v += bias[col0 + j];
                    atomicAdd(&C1[row * DMLP + col0 + j], v);
                }
            } else {
                int col0 = n0 - 4096 + tc * 4;
                #pragma unroll
                for (int j = 0; j < 4; ++j)
                    atomicAdd(&C2[row * 128 + col0 + j], acc[i][j]);
            }
        }
    }
}

// ---------------------------------------------------------------------------
// Mb[128][4096] bf16 = U(113x1024, zero-pad to 128) * Wo(1024x4096)
// BM=64(v), BN=32(m), grid (128,2)
// ---------------------------------------------------------------------------
__global__ __launch_bounds__(256) void k_gemm_m(
    unsigned short* __restrict__ Mb,
    const float* __restrict__ U,
    const float* __restrict__ Wo)
{
    __shared__ float Ua[32][68];
    __shared__ float Wb2[32][36];

    const int tid = threadIdx.x;
    const int m0 = blockIdx.x * 32;
    const int v0 = blockIdx.y * 64;
    const int sr = tid >> 2, sc = (tid & 3) * 8;
    const int swr = tid >> 3, swc = (tid & 7) * 4;
    const int tv = tid >> 3, tc = tid & 7;

    const float* uptr = (v0 + sr < PMOD) ? (U + (v0 + sr) * DM) : nullptr;

    float acc[2][4];
    #pragma unroll
    for (int i = 0; i < 2; ++i)
        #pragma unroll
        for (int j = 0; j < 4; ++j) acc[i][j] = 0.f;

    for (int k0 = 0; k0 < DM; k0 += 32) {
        float ua[8];
        if (uptr) {
            f32x4 v0v = *(const f32x4*)(uptr + k0 + sc);
            f32x4 v1v = *(const f32x4*)(uptr + k0 + sc + 4);
            ua[0]=v0v[0]; ua[1]=v0v[1]; ua[2]=v0v[2]; ua[3]=v0v[3];
            ua[4]=v1v[0]; ua[5]=v1v[1]; ua[6]=v1v[2]; ua[7]=v1v[3];
        } else {
            #pragma unroll
            for (int c = 0; c < 8; ++c) ua[c] = 0.f;
        }
        f32x4 wv = *(const f32x4*)(Wo + (k0 + swr) * DMLP + m0 + swc);
        if (k0) __syncthreads();
        #pragma unroll
        for (int c = 0; c < 8; ++c) Ua[sc + c][sr] = ua[c];
        *(f32x4*)&Wb2[swr][swc] = wv;
        __syncthreads();

        #pragma unroll 8
        for (int k = 0; k < 32; ++k) {
            float a0 = Ua[k][tv * 2], a1 = Ua[k][tv * 2 + 1];
            f32x4 b4 = *(const f32x4*)&Wb2[k][tc * 4];
            #pragma unroll
            for (int j = 0; j < 4; ++j) {
                acc[0][j] += a0 * b4[j];
                acc[1][j] += a1 * b4[j];
            }
        }
    }

    #pragma unroll
    for (int i = 0; i < 2; ++i) {
        int v = v0 + tv * 2 + i;
        ushort4v pk;
        #pragma unroll
        for (int j = 0; j < 4; ++j) pk[j] = (unsigned short)f2bf(acc[i][j]);
        *(ushort4v*)&Mb[v * DMLP + m0 + tc * 4] = pk;
    }
}

// ---------------------------------------------------------------------------
// Pair GEMM (MFMA bf16), split-K=8, atomicAdd into zeroed LT.
// block = (a, b-tile of 64 [non-overlapping], k-slice of 512)
//   h[m] = relu(H[a][m] + H[113+b][m])   (const+bias folded into H[a])
//   LT[a*113+b][v] += sum_m h[m]*Mb[v][m]; slice0 adds La+Lb+L227
// ---------------------------------------------------------------------------
__global__ __launch_bounds__(256) void k_pair_gemm(
    float* __restrict__ LT,
    const float* __restrict__ H,
    const unsigned short* __restrict__ Mb,
    const float* __restrict__ L)
{
    __shared__ short hA[64 * 72];
    __shared__ short mB[128 * 72];

    const int tid = threadIdx.x;
    const int a = blockIdx.x;
    const int b0 = blockIdx.y * 64;
    const int kbeg = blockIdx.z * 512;
    const bool slice0 = (blockIdx.z == 0);

    const int sr = tid >> 2, sq = (tid & 3) * 16;
    const int brow = b0 + sr;
    const int brc = brow < PMOD ? brow : PMOD - 1;   // clamp pad rows
    const float* pA = H + a * DMLP;
    const float* pB = H + (PMOD + brc) * DMLP;

    const int mv = tid >> 1, mk = (tid & 1) * 32;
    const unsigned short* pM = Mb + mv * DMLP + mk;

    const int lane = tid & 63, w = tid >> 6;
    const int wr = w >> 1, wc = w & 1;
    const int lr = lane & 15, lg = lane >> 4;

    f32x4 acc[2][4];
    #pragma unroll
    for (int i = 0; i < 2; ++i)
        #pragma unroll
        for (int j = 0; j < 4; ++j) acc[i][j] = 0.f;

    for (int k0 = kbeg; k0 < kbeg + 512; k0 += 64) {
        {
            short8 u0, u1;
            #pragma unroll
            for (int c4 = 0; c4 < 4; ++c4) {
                f32x4 va = *(const f32x4*)(pA + k0 + sq + c4 * 4);
                f32x4 vb = *(const f32x4*)(pB + k0 + sq + c4 * 4);
                #pragma unroll
                for (int e = 0; e < 4; ++e) {
                    float hv = fmaxf(va[e] + vb[e], 0.f);
                    short bv = f2bf(hv);
                    if (c4 < 2) u0[c4 * 4 + e] = bv;
                    else        u1[(c4 - 2) * 4 + e] = bv;
                }
            }
            const short8* s = (const short8*)(pM + k0);
            short8 t0 = s[0], t1 = s[1], t2 = s[2], t3 = s[3];
            if (k0 != kbeg) __syncthreads();
            *(short8*)&hA[sr * 72 + sq] = u0;
            *(short8*)&hA[sr * 72 + sq + 8] = u1;
            *(short8*)&mB[mv * 72 + mk] = t0;
            *(short8*)&mB[mv * 72 + mk + 8] = t1;
            *(short8*)&mB[mv * 72 + mk + 16] = t2;
            *(short8*)&mB[mv * 72 + mk + 24] = t3;
        }
        __syncthreads();

        #pragma unroll
        for (int ks = 0; ks < 2; ++ks) {
            short8 af[2], bf[4];
            #pragma unroll
            for (int i = 0; i < 2; ++i)
                af[i] = *(const short8*)&hA[(wr * 32 + i * 16 + lr) * 72 + ks * 32 + lg * 8];
            #pragma unroll
            for (int j = 0; j < 4; ++j)
                bf[j] = *(const short8*)&mB[(wc * 64 + j * 16 + lr) * 72 + ks * 32 + lg * 8];
            #pragma unroll
            for (int i = 0; i < 2; ++i)
                #pragma unroll
                for (int j = 0; j < 4; ++j)
                    acc[i][j] = __builtin_amdgcn_mfma_f32_16x16x32_bf16(af[i], bf[j], acc[i][j], 0, 0, 0);
        }
    }

    const float* La = L + a * 128;
    const float* Lb0 = L + PMOD * 128;
    const float* Lc = L + 227 * 128;
    #pragma unroll
    for (int i = 0; i < 2; ++i) {
        #pragma unroll
        for (int q = 0; q < 4; ++q) {
            int b = b0 + wr * 32 + i * 16 + lg * 4 + q;
            if (b >= PMOD) continue;
            float* dst = LT + (size_t)(a * PMOD + b) * 128;
            #pragma unroll
            for (int j = 0; j < 4; ++j) {
                int col = wc * 64 + j * 16 + lr;
                float val = acc[i][j][q];
                if (slice0) val += La[col] + Lb0[b * 128 + col] + Lc[col];
                atomicAdd(&dst[col], val);
            }
        }
    }
}

// ---------------------------------------------------------------------------
__global__ __launch_bounds__(256) void k_gather(
    float* __restrict__ out, const float* __restrict__ LT,
    const int* __restrict__ a, const int* __restrict__ b)
{
    int g = blockIdx.x * 256 + threadIdx.x;
    if (g >= NBATCH * PMOD) return;
    unsigned int i = (unsigned)g / 113u;
    unsigned int v = (unsigned)g - i * 113u;
    unsigned int pair = (unsigned)a[i] * 113u + (unsigned)b[i];
    out[g] = LT[(size_t)pair * 128 + v];
}

// ---------------------------------------------------------------------------
extern "C" void kernel_launch(void* const* d_in, const int* in_sizes, int n_in,
                              void* d_out, int out_size, void* d_ws, size_t ws_size,
                              hipStream_t stream)
{
    const int*   a   = (const int*)d_in[0];
    const int*   b   = (const int*)d_in[1];
    const float* E   = (const float*)d_in[2];
    const float* pos = (const float*)d_in[3];
    const float* Wi  = (const float*)d_in[4];
    const float* bi  = (const float*)d_in[5];
    const float* Wo  = (const float*)d_in[6];
    const float* bo  = (const float*)d_in[7];
    const float* U   = (const float*)d_in[8];
    float* out = (float*)d_out;

    float* V2 = (float*)d_ws;                  // 228*1024
    float* F  = V2 + 228 * DM;                 // 1024*1024
    float* T  = F + DM * DM;                   // 228*1024   ┐
    float* H  = T + 228 * DM;                  // 228*4096   │ zeroed
    float* L  = H + 228 * DMLP;                // 228*128    │ together
    float* LT = L + 228 * 128;                 // 12800*128  ┘
    unsigned short* Mb = (unsigned short*)(LT + 12800 * 128);  // 128*4096 bf16

    size_t zero_bytes = (size_t)(228 * DM + 228 * DMLP + 228 * 128 + 12800 * 128) * 4;
    hipMemsetAsync(T, 0, zero_bytes, stream);

    k_fmat<<<DM, 256, 0, stream>>>(F);
    k_v2<<<226, 256, 0, stream>>>(V2, E, pos);
    k_gemm_m<<<dim3(128, 2), 256, 0, stream>>>(Mb, U, Wo);
    k_gemm<0><<<dim3(16, 4, 8), 256, 0, stream>>>(T, nullptr, V2, 226, F, nullptr,
                                                  nullptr, E, pos, bo, 128);
    k_gemm<1><<<dim3(66, 4, 4), 256, 0, stream>>>(H, L, T, 228, Wi, U,
                                                  bi, nullptr, nullptr, nullptr, 256);
    k_pair_gemm<<<dim3(PMOD, 2, 8), 256, 0, stream>>>(LT, H, Mb, L);
    k_gather<<<(NBATCH * PMOD + 255) / 256, 256, 0, stream>>>(out, LT, a, b);

    (void)in_sizes; (void)n_in; (void)out_size; (void)ws_size;
}

// Round 4
// 197.226 us; speedup vs baseline: 2.9139x; 1.6009x over previous
//
#include <hip/hip_runtime.h>

typedef __attribute__((ext_vector_type(4))) float f32x4;
typedef __attribute__((ext_vector_type(8))) short short8;

#define PMOD 113
#define DM 1024
#define DMLP 4096
#define NBATCH 16384
#define SQRT3_2 0.86602540378443865f
#define CSTEP 6.1359231515425649e-3f   // 2*pi/1024
#define LTSTRIDE (12800 * 128)

__device__ __forceinline__ short f2bf(float x) {
    unsigned int u = __builtin_bit_cast(unsigned int, x);
    u += 0x7FFFu + ((u >> 16) & 1u);
    return (short)(u >> 16);
}
__device__ __forceinline__ float bf2f(short s) {
    return __builtin_bit_cast(float, (unsigned int)(unsigned short)s << 16);
}
__device__ __forceinline__ void cvt16(const float* p, short8& o0, short8& o1) {
    #pragma unroll
    for (int c4 = 0; c4 < 4; ++c4) {
        f32x4 v = *(const f32x4*)(p + c4 * 4);
        #pragma unroll
        for (int e = 0; e < 4; ++e) {
            short s = f2bf(v[e]);
            if (c4 < 2) o0[c4 * 4 + e] = s; else o1[(c4 - 2) * 4 + e] = s;
        }
    }
}

// ---------------------------------------------------------------------------
// Fb[1024][1024] bf16 folded real-DFT basis:
//   k<=512: cos(2pi f k/1024); k>512: sin(2pi f (k-512)/1024)
// ---------------------------------------------------------------------------
__global__ __launch_bounds__(256) void k_fmat(unsigned short* __restrict__ Fb)
{
    const int f = blockIdx.x, tid = threadIdx.x;
    for (int k = tid; k < DM; k += 256) {
        float v;
        if (k <= 512) v = cosf((float)((f * k) & 1023) * CSTEP);
        else          v = sinf((float)((f * (k - 512)) & 1023) * CSTEP);
        Fb[f * DM + k] = (unsigned short)f2bf(v);
    }
}

// ---------------------------------------------------------------------------
// V2b[228][1024] bf16 folded DFT coefficients (const row folded into t<113).
// Rows 226,227 zeroed.
// ---------------------------------------------------------------------------
__global__ __launch_bounds__(256) void k_v2(
    unsigned short* __restrict__ V2b, const float* __restrict__ E,
    const float* __restrict__ pos)
{
    const int t = blockIdx.x, tid = threadIdx.x;
    if (t >= 226) {
        for (int k = tid; k < DM; k += 256) V2b[t * DM + k] = 0;
        return;
    }
    __shared__ float vc[DM];
    __shared__ float vs[DM];

    if (t < PMOD) {
        const float* e = E + t * DM;
        const float* e2 = E + PMOD * DM;
        for (int d = tid; d < DM; d += 256) {
            float e2v = e2[d] + pos[2 * DM + d];
            vc[d] = e[d] + pos[d] - 0.5f * pos[DM + d] - 0.5f * e2v;
            vs[d] = SQRT3_2 * (pos[DM + d] - e2v);
        }
    } else {
        const float* e = E + (t - PMOD) * DM;
        for (int d = tid; d < DM; d += 256) {
            float x = e[d];
            vc[d] = -0.5f * x;
            vs[d] = SQRT3_2 * x;
        }
    }
    __syncthreads();

    for (int k = tid; k < DM; k += 256) {
        float o;
        if (k == 0)        o = vc[0];
        else if (k < 512)  o = vc[k] + vc[1024 - k];
        else if (k == 512) o = vc[512];
        else               o = vs[k - 512] - vs[1536 - k];
        V2b[t * DM + k] = (unsigned short)f2bf(o);
    }
}

// ---------------------------------------------------------------------------
// Wob[4096][1024] bf16 = transpose(Wo[1024][4096]) ; 64x64 LDS tiles
// ---------------------------------------------------------------------------
__global__ __launch_bounds__(256) void k_tcvt(
    unsigned short* __restrict__ Wob, const float* __restrict__ Wo)
{
    __shared__ float tile[64][65];
    const int m0 = blockIdx.x * 64;   // column block of Wo (= row block of Wob)
    const int d0 = blockIdx.y * 64;   // row block of Wo
    const int tid = threadIdx.x;
    #pragma unroll
    for (int it = 0; it < 16; ++it) {
        int idx = tid + it * 256;     // 0..4095
        int r = idx >> 6, c = idx & 63;
        tile[c][r] = Wo[(d0 + r) * DMLP + m0 + c];
    }
    __syncthreads();
    #pragma unroll
    for (int it = 0; it < 16; ++it) {
        int idx = tid + it * 256;
        int r = idx >> 6, c = idx & 63;
        Wob[(m0 + r) * DM + d0 + c] = (unsigned short)f2bf(tile[r][c]);
    }
}

// ---------------------------------------------------------------------------
// bf16 MFMA NT GEMM, BM=BN=64, BK=64, 4 waves (2x2), per-wave 32x32.
// MODE 0: Tb[228][1024] = V2b . Fb^T ; rows<113 += e2; row227 += bo  (bf16 out)
// MODE 1: A=Tb, B: n<4096 Wi(f32) -> Hb bf16 (+bi rows<113); n>=4096 U(f32)->L f32
// MODE 2: Mb[128][4096] = U(f32) . Wob^T (bf16 out)
// ---------------------------------------------------------------------------
template<int MODE>
__global__ __launch_bounds__(256) void k_mfma(
    unsigned short* __restrict__ C1, float* __restrict__ C2,
    const void* __restrict__ Av, const void* __restrict__ B1v,
    const float* __restrict__ B2, const float* __restrict__ bias,
    const float* __restrict__ E, const float* __restrict__ pos,
    const float* __restrict__ bo)
{
    __shared__ short sA[64 * 72];
    __shared__ short sB[64 * 72];
    const int tid = threadIdx.x;
    const int n0 = blockIdx.x * 64;
    const int row0 = blockIdx.y * 64;
    const int sr = tid >> 2, sq = (tid & 3) * 16;
    const int lane = tid & 63, w = tid >> 6;
    const int wr = w >> 1, wc = w & 1;
    const int lr = lane & 15, lg = lane >> 4;

    const unsigned short* Ab = nullptr; const float* Af = nullptr;
    {
        int r = row0 + sr;
        if (MODE == 2) { if (r < PMOD) Af = (const float*)Av + r * DM; }
        else           { if (r < 228)  Ab = (const unsigned short*)Av + r * DM; }
    }
    const unsigned short* Bb = nullptr; const float* Bf = nullptr;
    {
        int n = n0 + sr;
        if (MODE == 1) {
            if (n < 4096) Bf = (const float*)B1v + n * DM;
            else if (n - 4096 < PMOD) Bf = B2 + (n - 4096) * DM;
        } else {
            Bb = (const unsigned short*)B1v + n * DM;
        }
    }

    f32x4 acc[2][2];
    #pragma unroll
    for (int i = 0; i < 2; ++i)
        #pragma unroll
        for (int j = 0; j < 2; ++j) acc[i][j] = 0.f;

    for (int k0 = 0; k0 < DM; k0 += 64) {
        short8 a0, a1, b0, b1;
        if (MODE == 2) {
            if (Af) cvt16(Af + k0 + sq, a0, a1);
            else { a0 = 0; a1 = 0; }
        } else {
            if (Ab) { a0 = ((const short8*)(Ab + k0 + sq))[0];
                      a1 = ((const short8*)(Ab + k0 + sq))[1]; }
            else { a0 = 0; a1 = 0; }
        }
        if (MODE == 1) {
            if (Bf) cvt16(Bf + k0 + sq, b0, b1);
            else { b0 = 0; b1 = 0; }
        } else {
            b0 = ((const short8*)(Bb + k0 + sq))[0];
            b1 = ((const short8*)(Bb + k0 + sq))[1];
        }
        if (k0) __syncthreads();
        *(short8*)&sA[sr * 72 + sq] = a0;
        *(short8*)&sA[sr * 72 + sq + 8] = a1;
        *(short8*)&sB[sr * 72 + sq] = b0;
        *(short8*)&sB[sr * 72 + sq + 8] = b1;
        __syncthreads();

        #pragma unroll
        for (int ks = 0; ks < 2; ++ks) {
            short8 af[2], bfr[2];
            #pragma unroll
            for (int i = 0; i < 2; ++i)
                af[i] = *(const short8*)&sA[(wr * 32 + i * 16 + lr) * 72 + ks * 32 + lg * 8];
            #pragma unroll
            for (int j = 0; j < 2; ++j)
                bfr[j] = *(const short8*)&sB[(wc * 32 + j * 16 + lr) * 72 + ks * 32 + lg * 8];
            #pragma unroll
            for (int i = 0; i < 2; ++i)
                #pragma unroll
                for (int j = 0; j < 2; ++j)
                    acc[i][j] = __builtin_amdgcn_mfma_f32_16x16x32_bf16(af[i], bfr[j], acc[i][j], 0, 0, 0);
        }
    }

    #pragma unroll
    for (int i = 0; i < 2; ++i) {
        #pragma unroll
        for (int q = 0; q < 4; ++q) {
            int r = row0 + wr * 32 + i * 16 + lg * 4 + q;
            #pragma unroll
            for (int j = 0; j < 2; ++j) {
                int cg = n0 + wc * 32 + j * 16 + lr;
                float v = acc[i][j][q];
                if (MODE == 0) {
                    if (r < 228) {
                        if (r < PMOD) v += E[PMOD * DM + cg] + pos[2 * DM + cg];
                        if (r == 227) v += bo[cg];
                        C1[r * DM + cg] = (unsigned short)f2bf(v);
                    }
                } else if (MODE == 1) {
                    if (r < 228) {
                        if (n0 < 4096) {
                            if (r < PMOD) v += bias[cg];
                            C1[r * DMLP + cg] = (unsigned short)f2bf(v);
                        } else {
                            C2[r * 128 + cg - 4096] = v;
                        }
                    }
                } else {
                    C1[r * DMLP + cg] = (unsigned short)f2bf(v);
                }
            }
        }
    }
}

// ---------------------------------------------------------------------------
// Pair GEMM (MFMA bf16), split-K=4, plain bf16 stores into per-slice partials.
// block = (a, b-tile of 64, k-slice of 1024)
//   h[m] = relu(Hb[a][m] + Hb[113+b][m]); LTp[z][a*113+b][v] = partial + (z==0: L-terms)
// ---------------------------------------------------------------------------
__global__ __launch_bounds__(256) void k_pair_gemm(
    unsigned short* __restrict__ LTp,
    const unsigned short* __restrict__ Hb,
    const unsigned short* __restrict__ Mb,
    const float* __restrict__ L)
{
    __shared__ short hA[64 * 72];
    __shared__ short mB[128 * 72];

    const int tid = threadIdx.x;
    const int a = blockIdx.x;
    const int b0 = blockIdx.y * 64;
    const int kbeg = blockIdx.z * 1024;
    const bool slice0 = (blockIdx.z == 0);
    unsigned short* outp = LTp + (size_t)blockIdx.z * LTSTRIDE;

    const int sr = tid >> 2, sq = (tid & 3) * 16;
    const int brow = b0 + sr;
    const int brc = brow < PMOD ? brow : PMOD - 1;
    const unsigned short* pA = Hb + a * DMLP;
    const unsigned short* pB = Hb + (PMOD + brc) * DMLP;

    const int mv = tid >> 1, mk = (tid & 1) * 32;
    const unsigned short* pM = Mb + mv * DMLP + mk;

    const int lane = tid & 63, w = tid >> 6;
    const int wr = w >> 1, wc = w & 1;
    const int lr = lane & 15, lg = lane >> 4;

    f32x4 acc[2][4];
    #pragma unroll
    for (int i = 0; i < 2; ++i)
        #pragma unroll
        for (int j = 0; j < 4; ++j) acc[i][j] = 0.f;

    for (int k0 = kbeg; k0 < kbeg + 1024; k0 += 64) {
        short8 A0 = ((const short8*)(pA + k0 + sq))[0];
        short8 A1 = ((const short8*)(pA + k0 + sq))[1];
        short8 B0 = ((const short8*)(pB + k0 + sq))[0];
        short8 B1 = ((const short8*)(pB + k0 + sq))[1];
        short8 u0, u1;
        #pragma unroll
        for (int e = 0; e < 8; ++e) {
            u0[e] = f2bf(fmaxf(bf2f(A0[e]) + bf2f(B0[e]), 0.f));
            u1[e] = f2bf(fmaxf(bf2f(A1[e]) + bf2f(B1[e]), 0.f));
        }
        const short8* s = (const short8*)(pM + k0);
        short8 t0 = s[0], t1 = s[1], t2 = s[2], t3 = s[3];
        if (k0 != kbeg) __syncthreads();
        *(short8*)&hA[sr * 72 + sq] = u0;
        *(short8*)&hA[sr * 72 + sq + 8] = u1;
        *(short8*)&mB[mv * 72 + mk] = t0;
        *(short8*)&mB[mv * 72 + mk + 8] = t1;
        *(short8*)&mB[mv * 72 + mk + 16] = t2;
        *(short8*)&mB[mv * 72 + mk + 24] = t3;
        __syncthreads();

        #pragma unroll
        for (int ks = 0; ks < 2; ++ks) {
            short8 af[2], bf[4];
            #pragma unroll
            for (int i = 0; i < 2; ++i)
                af[i] = *(const short8*)&hA[(wr * 32 + i * 16 + lr) * 72 + ks * 32 + lg * 8];
            #pragma unroll
            for (int j = 0; j < 4; ++j)
                bf[j] = *(const short8*)&mB[(wc * 64 + j * 16 + lr) * 72 + ks * 32 + lg * 8];
            #pragma unroll
            for (int i = 0; i < 2; ++i)
                #pragma unroll
                for (int j = 0; j < 4; ++j)
                    acc[i][j] = __builtin_amdgcn_mfma_f32_16x16x32_bf16(af[i], bf[j], acc[i][j], 0, 0, 0);
        }
    }

    const float* La = L + a * 128;
    const float* Lb0 = L + PMOD * 128;
    const float* Lc = L + 227 * 128;
    #pragma unroll
    for (int i = 0; i < 2; ++i) {
        #pragma unroll
        for (int q = 0; q < 4; ++q) {
            int b = b0 + wr * 32 + i * 16 + lg * 4 + q;
            if (b >= PMOD) continue;
            unsigned short* dst = outp + (size_t)(a * PMOD + b) * 128;
            #pragma unroll
            for (int j = 0; j < 4; ++j) {
                int col = wc * 64 + j * 16 + lr;
                float val = acc[i][j][q];
                if (slice0) val += La[col] + Lb0[b * 128 + col] + Lc[col];
                dst[col] = (unsigned short)f2bf(val);
            }
        }
    }
}

// ---------------------------------------------------------------------------
// LT[p][v] = sum_z bf2f(LTp[z][p][v])
// ---------------------------------------------------------------------------
__global__ __launch_bounds__(256) void k_reduce(
    float* __restrict__ LT, const unsigned short* __restrict__ LTp)
{
    const int base = (blockIdx.x * 256 + threadIdx.x) * 8;
    float sum[8];
    #pragma unroll
    for (int e = 0; e < 8; ++e) sum[e] = 0.f;
    #pragma unroll
    for (int z = 0; z < 4; ++z) {
        short8 v = *(const short8*)(LTp + (size_t)z * LTSTRIDE + base);
        #pragma unroll
        for (int e = 0; e < 8; ++e) sum[e] += bf2f(v[e]);
    }
    f32x4 o0, o1;
    #pragma unroll
    for (int e = 0; e < 4; ++e) { o0[e] = sum[e]; o1[e] = sum[e + 4]; }
    *(f32x4*)&LT[base] = o0;
    *(f32x4*)&LT[base + 4] = o1;
}

// ---------------------------------------------------------------------------
__global__ __launch_bounds__(256) void k_gather(
    float* __restrict__ out, const float* __restrict__ LT,
    const int* __restrict__ a, const int* __restrict__ b)
{
    int g = blockIdx.x * 256 + threadIdx.x;
    if (g >= NBATCH * PMOD) return;
    unsigned int i = (unsigned)g / 113u;
    unsigned int v = (unsigned)g - i * 113u;
    unsigned int pair = (unsigned)a[i] * 113u + (unsigned)b[i];
    out[g] = LT[(size_t)pair * 128 + v];
}

// ---------------------------------------------------------------------------
extern "C" void kernel_launch(void* const* d_in, const int* in_sizes, int n_in,
                              void* d_out, int out_size, void* d_ws, size_t ws_size,
                              hipStream_t stream)
{
    const int*   a   = (const int*)d_in[0];
    const int*   b   = (const int*)d_in[1];
    const float* E   = (const float*)d_in[2];
    const float* pos = (const float*)d_in[3];
    const float* Wi  = (const float*)d_in[4];
    const float* bi  = (const float*)d_in[5];
    const float* Wo  = (const float*)d_in[6];
    const float* bo  = (const float*)d_in[7];
    const float* U   = (const float*)d_in[8];
    float* out = (float*)d_out;

    unsigned short* Fb  = (unsigned short*)d_ws;          // 1024*1024
    unsigned short* V2b = Fb + 1024 * 1024;               // 228*1024
    unsigned short* Tb  = V2b + 228 * 1024;               // 228*1024
    unsigned short* Hb  = Tb + 228 * 1024;                // 228*4096
    unsigned short* Wob = Hb + 228 * 4096;                // 4096*1024
    unsigned short* Mb  = Wob + 4096 * 1024;              // 128*4096
    unsigned short* LTp = Mb + 128 * 4096;                // 4 * 12800*128
    float* L  = (float*)(LTp + 4 * LTSTRIDE);             // 228*128
    float* LT = L + 228 * 128;                            // 12800*128

    k_fmat<<<DM, 256, 0, stream>>>(Fb);
    k_v2<<<228, 256, 0, stream>>>(V2b, E, pos);
    k_tcvt<<<dim3(64, 16), 256, 0, stream>>>(Wob, Wo);
    k_mfma<0><<<dim3(16, 4), 256, 0, stream>>>(Tb, nullptr, V2b, Fb, nullptr,
                                               nullptr, E, pos, bo);
    k_mfma<1><<<dim3(66, 4), 256, 0, stream>>>(Hb, L, Tb, Wi, U,
                                               bi, nullptr, nullptr, nullptr);
    k_mfma<2><<<dim3(64, 2), 256, 0, stream>>>(Mb, nullptr, U, Wob, nullptr,
                                               nullptr, nullptr, nullptr, nullptr);
    k_pair_gemm<<<dim3(PMOD, 2, 4), 256, 0, stream>>>(LTp, Hb, Mb, L);
    k_reduce<<<LTSTRIDE / 8 / 256, 256, 0, stream>>>(LT, LTp);
    k_gather<<<(NBATCH * PMOD + 255) / 256, 256, 0, stream>>>(out, LT, a, b);

    (void)in_sizes; (void)n_in; (void)out_size; (void)ws_size;
}

// Round 5
// 182.694 us; speedup vs baseline: 3.1457x; 1.0795x over previous
//
#include <hip/hip_runtime.h>

typedef __attribute__((ext_vector_type(4))) float f32x4;
typedef __attribute__((ext_vector_type(8))) short short8;

#define PMOD 113
#define DM 1024
#define DMLP 4096
#define NBATCH 16384
#define SQRT3_2 0.86602540378443865f
#define CSTEP 6.1359231515425649e-3f   // 2*pi/1024
#define LTSTRIDE (12800 * 128)

__device__ __forceinline__ short f2bf(float x) {
    unsigned int u = __builtin_bit_cast(unsigned int, x);
    u += 0x7FFFu + ((u >> 16) & 1u);
    return (short)(u >> 16);
}
__device__ __forceinline__ float bf2f(short s) {
    return __builtin_bit_cast(float, (unsigned int)(unsigned short)s << 16);
}
__device__ __forceinline__ void cvt16(const float* p, short8& o0, short8& o1) {
    #pragma unroll
    for (int c4 = 0; c4 < 4; ++c4) {
        f32x4 v = *(const f32x4*)(p + c4 * 4);
        #pragma unroll
        for (int e = 0; e < 4; ++e) {
            short s = f2bf(v[e]);
            if (c4 < 2) o0[c4 * 4 + e] = s; else o1[(c4 - 2) * 4 + e] = s;
        }
    }
}

// ---------------------------------------------------------------------------
// k_prep: merged elementwise precompute. blockIdx.x ranges:
//   [0,1024)      : Fb[f][k] folded DFT basis (bf16)
//   [1024,1252)   : V2b[t][k] folded coefficients (bf16), rows 226/227 zero
//   [1252,2276)   : Wob = transpose(Wo) as bf16, 64x64 tiles
// ---------------------------------------------------------------------------
__global__ __launch_bounds__(256) void k_prep(
    unsigned short* __restrict__ Fb, unsigned short* __restrict__ V2b,
    unsigned short* __restrict__ Wob,
    const float* __restrict__ E, const float* __restrict__ pos,
    const float* __restrict__ Wo)
{
    __shared__ float smem[64 * 65];
    const int blk = blockIdx.x, tid = threadIdx.x;

    if (blk < 1024) {
        const int f = blk;
        for (int k = tid; k < DM; k += 256) {
            float v;
            if (k <= 512) v = cosf((float)((f * k) & 1023) * CSTEP);
            else          v = sinf((float)((f * (k - 512)) & 1023) * CSTEP);
            Fb[f * DM + k] = (unsigned short)f2bf(v);
        }
    } else if (blk < 1252) {
        const int t = blk - 1024;
        if (t >= 226) {
            for (int k = tid; k < DM; k += 256) V2b[t * DM + k] = 0;
            return;
        }
        float* vc = smem;
        float* vs = smem + 1024;
        if (t < PMOD) {
            const float* e = E + t * DM;
            const float* e2 = E + PMOD * DM;
            for (int d = tid; d < DM; d += 256) {
                float e2v = e2[d] + pos[2 * DM + d];
                vc[d] = e[d] + pos[d] - 0.5f * pos[DM + d] - 0.5f * e2v;
                vs[d] = SQRT3_2 * (pos[DM + d] - e2v);
            }
        } else {
            const float* e = E + (t - PMOD) * DM;
            for (int d = tid; d < DM; d += 256) {
                float x = e[d];
                vc[d] = -0.5f * x;
                vs[d] = SQRT3_2 * x;
            }
        }
        __syncthreads();
        for (int k = tid; k < DM; k += 256) {
            float o;
            if (k == 0)        o = vc[0];
            else if (k < 512)  o = vc[k] + vc[1024 - k];
            else if (k == 512) o = vc[512];
            else               o = vs[k - 512] - vs[1536 - k];
            V2b[t * DM + k] = (unsigned short)f2bf(o);
        }
    } else {
        const int idx = blk - 1252;
        const int m0 = (idx & 63) * 64;
        const int d0 = (idx >> 6) * 64;
        float (*tile)[65] = (float(*)[65])smem;
        #pragma unroll
        for (int it = 0; it < 16; ++it) {
            int i2 = tid + it * 256;
            int r = i2 >> 6, c = i2 & 63;
            tile[c][r] = Wo[(d0 + r) * DMLP + m0 + c];
        }
        __syncthreads();
        #pragma unroll
        for (int it = 0; it < 16; ++it) {
            int i2 = tid + it * 256;
            int r = i2 >> 6, c = i2 & 63;
            Wob[(m0 + r) * DM + d0 + c] = (unsigned short)f2bf(tile[r][c]);
        }
    }
}

// ---------------------------------------------------------------------------
// bf16 MFMA NT GEMM body, BM=BN=64, BK=64, 4 waves (2x2), per-wave 32x32.
// MODE 0: Tb[228][1024] = V2b . Fb^T ; rows<113 += e2; row227 += bo (bf16 out)
// MODE 1: A=Tb, B: n<4096 Wi(f32)->Hb bf16 (+bi rows<113); n>=4096 U(f32)->L f32
// MODE 2: Mb[128][4096] = U(f32) . Wob^T (bf16 out)
// ---------------------------------------------------------------------------
template<int MODE>
__device__ __forceinline__ void mfma_body(
    int n0, int row0,
    unsigned short* __restrict__ C1, float* __restrict__ C2,
    const void* __restrict__ Av, const void* __restrict__ B1v,
    const float* __restrict__ B2, const float* __restrict__ bias,
    const float* __restrict__ E, const float* __restrict__ pos,
    const float* __restrict__ bo, short* sA, short* sB)
{
    const int tid = threadIdx.x;
    const int sr = tid >> 2, sq = (tid & 3) * 16;
    const int lane = tid & 63, w = tid >> 6;
    const int wr = w >> 1, wc = w & 1;
    const int lr = lane & 15, lg = lane >> 4;

    const unsigned short* Ab = nullptr; const float* Af = nullptr;
    {
        int r = row0 + sr;
        if (MODE == 2) { if (r < PMOD) Af = (const float*)Av + r * DM; }
        else           { if (r < 228)  Ab = (const unsigned short*)Av + r * DM; }
    }
    const unsigned short* Bb = nullptr; const float* Bf = nullptr;
    {
        int n = n0 + sr;
        if (MODE == 1) {
            if (n < 4096) Bf = (const float*)B1v + n * DM;
            else if (n - 4096 < PMOD) Bf = B2 + (n - 4096) * DM;
        } else {
            Bb = (const unsigned short*)B1v + n * DM;
        }
    }

    f32x4 acc[2][2];
    #pragma unroll
    for (int i = 0; i < 2; ++i)
        #pragma unroll
        for (int j = 0; j < 2; ++j) acc[i][j] = 0.f;

    for (int k0 = 0; k0 < DM; k0 += 64) {
        short8 a0, a1, b0, b1;
        if (MODE == 2) {
            if (Af) cvt16(Af + k0 + sq, a0, a1);
            else { a0 = 0; a1 = 0; }
        } else {
            if (Ab) { a0 = ((const short8*)(Ab + k0 + sq))[0];
                      a1 = ((const short8*)(Ab + k0 + sq))[1]; }
            else { a0 = 0; a1 = 0; }
        }
        if (MODE == 1) {
            if (Bf) cvt16(Bf + k0 + sq, b0, b1);
            else { b0 = 0; b1 = 0; }
        } else {
            b0 = ((const short8*)(Bb + k0 + sq))[0];
            b1 = ((const short8*)(Bb + k0 + sq))[1];
        }
        if (k0) __syncthreads();
        *(short8*)&sA[sr * 72 + sq] = a0;
        *(short8*)&sA[sr * 72 + sq + 8] = a1;
        *(short8*)&sB[sr * 72 + sq] = b0;
        *(short8*)&sB[sr * 72 + sq + 8] = b1;
        __syncthreads();

        #pragma unroll
        for (int ks = 0; ks < 2; ++ks) {
            short8 af[2], bfr[2];
            #pragma unroll
            for (int i = 0; i < 2; ++i)
                af[i] = *(const short8*)&sA[(wr * 32 + i * 16 + lr) * 72 + ks * 32 + lg * 8];
            #pragma unroll
            for (int j = 0; j < 2; ++j)
                bfr[j] = *(const short8*)&sB[(wc * 32 + j * 16 + lr) * 72 + ks * 32 + lg * 8];
            #pragma unroll
            for (int i = 0; i < 2; ++i)
                #pragma unroll
                for (int j = 0; j < 2; ++j)
                    acc[i][j] = __builtin_amdgcn_mfma_f32_16x16x32_bf16(af[i], bfr[j], acc[i][j], 0, 0, 0);
        }
    }

    #pragma unroll
    for (int i = 0; i < 2; ++i) {
        #pragma unroll
        for (int q = 0; q < 4; ++q) {
            int r = row0 + wr * 32 + i * 16 + lg * 4 + q;
            #pragma unroll
            for (int j = 0; j < 2; ++j) {
                int cg = n0 + wc * 32 + j * 16 + lr;
                float v = acc[i][j][q];
                if (MODE == 0) {
                    if (r < 228) {
                        if (r < PMOD) v += E[PMOD * DM + cg] + pos[2 * DM + cg];
                        if (r == 227) v += bo[cg];
                        C1[r * DM + cg] = (unsigned short)f2bf(v);
                    }
                } else if (MODE == 1) {
                    if (r < 228) {
                        if (n0 < 4096) {
                            if (r < PMOD) v += bias[cg];
                            C1[r * DMLP + cg] = (unsigned short)f2bf(v);
                        } else {
                            C2[r * 128 + cg - 4096] = v;
                        }
                    }
                } else {
                    if (r < 128) C1[r * DMLP + cg] = (unsigned short)f2bf(v);
                }
            }
        }
    }
}

// Merged MODE0 (64 blocks) + MODE2 (128 blocks): independent, fill the chip.
__global__ __launch_bounds__(256) void k_m02(
    unsigned short* __restrict__ Tb, unsigned short* __restrict__ Mb,
    const unsigned short* __restrict__ V2b, const unsigned short* __restrict__ Fb,
    const float* __restrict__ U, const unsigned short* __restrict__ Wob,
    const float* __restrict__ E, const float* __restrict__ pos,
    const float* __restrict__ bo)
{
    __shared__ short sA[64 * 72];
    __shared__ short sB[64 * 72];
    const int blk = blockIdx.x;
    if (blk < 64) {
        mfma_body<0>((blk & 15) * 64, (blk >> 4) * 64, Tb, nullptr, V2b, Fb,
                     nullptr, nullptr, E, pos, bo, sA, sB);
    } else {
        int i = blk - 64;
        mfma_body<2>((i & 63) * 64, (i >> 6) * 64, Mb, nullptr, U, Wob,
                     nullptr, nullptr, nullptr, nullptr, nullptr, sA, sB);
    }
}

__global__ __launch_bounds__(256) void k_m1(
    unsigned short* __restrict__ Hb, float* __restrict__ L,
    const unsigned short* __restrict__ Tb, const float* __restrict__ Wi,
    const float* __restrict__ U, const float* __restrict__ bi)
{
    __shared__ short sA[64 * 72];
    __shared__ short sB[64 * 72];
    mfma_body<1>(blockIdx.x * 64, blockIdx.y * 64, Hb, L, Tb, Wi, U, bi,
                 nullptr, nullptr, nullptr, sA, sB);
}

// ---------------------------------------------------------------------------
// Pair GEMM (MFMA bf16), split-K=4, register-prefetched staging,
// bf16 partial stores into per-slice buffers (no atomics).
// block = (a, b-tile of 64, k-slice of 1024)
//   h[m] = relu(Hb[a][m] + Hb[113+b][m]);
//   LTp[z][a*113+b][v] = partial (+ z==0: La+Lb+Lc terms)
// ---------------------------------------------------------------------------
__global__ __launch_bounds__(256) void k_pair_gemm(
    unsigned short* __restrict__ LTp,
    const unsigned short* __restrict__ Hb,
    const unsigned short* __restrict__ Mb,
    const float* __restrict__ L)
{
    __shared__ short hA[64 * 72];
    __shared__ short mB[128 * 72];

    const int tid = threadIdx.x;
    const int a = blockIdx.x;
    const int b0 = blockIdx.y * 64;
    const int kbeg = blockIdx.z * 1024;
    const bool slice0 = (blockIdx.z == 0);
    unsigned short* outp = LTp + (size_t)blockIdx.z * LTSTRIDE;

    const int sr = tid >> 2, sq = (tid & 3) * 16;
    const int brow = b0 + sr;
    const int brc = brow < PMOD ? brow : PMOD - 1;
    const unsigned short* pA = Hb + a * DMLP;
    const unsigned short* pB = Hb + (PMOD + brc) * DMLP;

    const int mv = tid >> 1, mk = (tid & 1) * 32;
    const unsigned short* pM = Mb + mv * DMLP + mk;

    const int lane = tid & 63, w = tid >> 6;
    const int wr = w >> 1, wc = w & 1;
    const int lr = lane & 15, lg = lane >> 4;

    f32x4 acc[2][4];
    #pragma unroll
    for (int i = 0; i < 2; ++i)
        #pragma unroll
        for (int j = 0; j < 4; ++j) acc[i][j] = 0.f;

    // ping-pong register tiles
    short8 rA0[2], rA1[2], rB0[2], rB1[2], rM[2][4];

    #define LOADT(ph, kc)                                              \
        do {                                                           \
            rA0[ph] = ((const short8*)(pA + (kc) + sq))[0];            \
            rA1[ph] = ((const short8*)(pA + (kc) + sq))[1];            \
            rB0[ph] = ((const short8*)(pB + (kc) + sq))[0];            \
            rB1[ph] = ((const short8*)(pB + (kc) + sq))[1];            \
            const short8* s_ = (const short8*)(pM + (kc));             \
            rM[ph][0] = s_[0]; rM[ph][1] = s_[1];                      \
            rM[ph][2] = s_[2]; rM[ph][3] = s_[3];                      \
        } while (0)

    LOADT(0, kbeg);

    for (int k0 = kbeg; k0 < kbeg + 1024; k0 += 128) {
        #pragma unroll
        for (int ph = 0; ph < 2; ++ph) {
            const int kc = k0 + ph * 64;
            if (kc + 64 < kbeg + 1024) LOADT(ph ^ 1, kc + 64);

            short8 u0, u1;
            #pragma unroll
            for (int e = 0; e < 8; ++e) {
                u0[e] = f2bf(fmaxf(bf2f(rA0[ph][e]) + bf2f(rB0[ph][e]), 0.f));
                u1[e] = f2bf(fmaxf(bf2f(rA1[ph][e]) + bf2f(rB1[ph][e]), 0.f));
            }
            if (kc != kbeg) __syncthreads();
            *(short8*)&hA[sr * 72 + sq] = u0;
            *(short8*)&hA[sr * 72 + sq + 8] = u1;
            *(short8*)&mB[mv * 72 + mk] = rM[ph][0];
            *(short8*)&mB[mv * 72 + mk + 8] = rM[ph][1];
            *(short8*)&mB[mv * 72 + mk + 16] = rM[ph][2];
            *(short8*)&mB[mv * 72 + mk + 24] = rM[ph][3];
            __syncthreads();

            #pragma unroll
            for (int ks = 0; ks < 2; ++ks) {
                short8 af[2], bf[4];
                #pragma unroll
                for (int i = 0; i < 2; ++i)
                    af[i] = *(const short8*)&hA[(wr * 32 + i * 16 + lr) * 72 + ks * 32 + lg * 8];
                #pragma unroll
                for (int j = 0; j < 4; ++j)
                    bf[j] = *(const short8*)&mB[(wc * 64 + j * 16 + lr) * 72 + ks * 32 + lg * 8];
                #pragma unroll
                for (int i = 0; i < 2; ++i)
                    #pragma unroll
                    for (int j = 0; j < 4; ++j)
                        acc[i][j] = __builtin_amdgcn_mfma_f32_16x16x32_bf16(af[i], bf[j], acc[i][j], 0, 0, 0);
            }
        }
    }
    #undef LOADT

    const float* La = L + a * 128;
    const float* Lb0 = L + PMOD * 128;
    const float* Lc = L + 227 * 128;
    #pragma unroll
    for (int i = 0; i < 2; ++i) {
        #pragma unroll
        for (int q = 0; q < 4; ++q) {
            int b = b0 + wr * 32 + i * 16 + lg * 4 + q;
            if (b >= PMOD) continue;
            unsigned short* dst = outp + (size_t)(a * PMOD + b) * 128;
            #pragma unroll
            for (int j = 0; j < 4; ++j) {
                int col = wc * 64 + j * 16 + lr;
                float val = acc[i][j][q];
                if (slice0) val += La[col] + Lb0[b * 128 + col] + Lc[col];
                dst[col] = (unsigned short)f2bf(val);
            }
        }
    }
}

// ---------------------------------------------------------------------------
// Gather + partial-slice reduce: out[i,v] = sum_z LTp[z][a_i*113+b_i][v]
// ---------------------------------------------------------------------------
__global__ __launch_bounds__(256) void k_gather(
    float* __restrict__ out, const unsigned short* __restrict__ LTp,
    const int* __restrict__ a, const int* __restrict__ b)
{
    int g = blockIdx.x * 256 + threadIdx.x;
    if (g >= NBATCH * PMOD) return;
    unsigned int i = (unsigned)g / 113u;
    unsigned int v = (unsigned)g - i * 113u;
    size_t off = (size_t)((unsigned)a[i] * 113u + (unsigned)b[i]) * 128 + v;
    float s = 0.f;
    #pragma unroll
    for (int z = 0; z < 4; ++z)
        s += bf2f(LTp[(size_t)z * LTSTRIDE + off]);
    out[g] = s;
}

// ---------------------------------------------------------------------------
extern "C" void kernel_launch(void* const* d_in, const int* in_sizes, int n_in,
                              void* d_out, int out_size, void* d_ws, size_t ws_size,
                              hipStream_t stream)
{
    const int*   a   = (const int*)d_in[0];
    const int*   b   = (const int*)d_in[1];
    const float* E   = (const float*)d_in[2];
    const float* pos = (const float*)d_in[3];
    const float* Wi  = (const float*)d_in[4];
    const float* bi  = (const float*)d_in[5];
    const float* Wo  = (const float*)d_in[6];
    const float* bo  = (const float*)d_in[7];
    const float* U   = (const float*)d_in[8];
    float* out = (float*)d_out;

    unsigned short* Fb  = (unsigned short*)d_ws;          // 1024*1024
    unsigned short* V2b = Fb + 1024 * 1024;               // 228*1024
    unsigned short* Tb  = V2b + 228 * 1024;               // 228*1024
    unsigned short* Hb  = Tb + 228 * 1024;                // 228*4096
    unsigned short* Wob = Hb + 228 * 4096;                // 4096*1024
    unsigned short* Mb  = Wob + 4096 * 1024;              // 128*4096
    unsigned short* LTp = Mb + 128 * 4096;                // 4 * LTSTRIDE
    float* L = (float*)(LTp + 4 * LTSTRIDE);              // 228*128

    k_prep<<<2276, 256, 0, stream>>>(Fb, V2b, Wob, E, pos, Wo);
    k_m02<<<192, 256, 0, stream>>>(Tb, Mb, V2b, Fb, U, Wob, E, pos, bo);
    k_m1<<<dim3(66, 4), 256, 0, stream>>>(Hb, L, Tb, Wi, U, bi);
    k_pair_gemm<<<dim3(PMOD, 2, 4), 256, 0, stream>>>(LTp, Hb, Mb, L);
    k_gather<<<(NBATCH * PMOD + 255) / 256, 256, 0, stream>>>(out, LTp, a, b);

    (void)in_sizes; (void)n_in; (void)out_size; (void)ws_size;
}